// Round 4
// baseline (227.499 us; speedup 1.0000x reference)
//
#include <hip/hip_runtime.h>
#include <cstdint>

__device__ __forceinline__ float leaky(float v) { return v >= 0.f ? v : 0.01f * v; }

// ================= Encoder: conv5x5 pad2 + leaky + fused 2x2 maxpool =================
template<int R, int CI, int CO, int COG>
__global__ void __launch_bounds__(256) enc_k(
    const float* __restrict__ src1, const float* __restrict__ src2,
    const float* __restrict__ w, const float* __restrict__ bias,
    float* __restrict__ c2, float* __restrict__ pout)
{
    constexpr int W = R, H = R, Wt = R / 2;
    constexpr int RPB = 256 / Wt;              // rows per block (even)
    __shared__ float ws[COG * CI * 25];
    __shared__ float pl[(RPB / 2) * COG * Wt];

    int t = threadIdx.x;
    int gid = blockIdx.x * 256 + t;
    int col = gid % Wt;
    int y = (gid / Wt) % H;
    int n = (gid / (Wt * H)) & 3;
    int g = gid / (Wt * H * 4);

    for (int i = t; i < COG * CI * 25; i += 256) ws[i] = w[g * COG * CI * 25 + i];
    __syncthreads();

    const float* sp = (n < 2) ? (src1 + (size_t)n * CI * H * W)
                              : (src2 + (size_t)(n - 2) * CI * H * W);
    int x0 = col * 2;

    float acc[COG][2];
#pragma unroll
    for (int cg = 0; cg < COG; ++cg) { float b0 = bias[g * COG + cg]; acc[cg][0] = b0; acc[cg][1] = b0; }

    bool okr[5], okc[3];
#pragma unroll
    for (int i = 0; i < 5; ++i) { int yy = y + i - 2; okr[i] = (yy >= 0) && (yy < H); }
#pragma unroll
    for (int j = 0; j < 3; ++j) { int xx = x0 + 2 * j - 2; okc[j] = (xx >= 0) && (xx < W); }

    for (int ci = 0; ci < CI; ++ci) {
        const float* s = sp + ci * H * W + (y - 2) * W + (x0 - 2);
        float p[5][6];
#pragma unroll
        for (int i = 0; i < 5; ++i) {
#pragma unroll
            for (int j = 0; j < 3; ++j) {
                if (okr[i] & okc[j]) {
                    float2 v = *(const float2*)(s + i * W + 2 * j);
                    p[i][2 * j] = v.x; p[i][2 * j + 1] = v.y;
                } else { p[i][2 * j] = 0.f; p[i][2 * j + 1] = 0.f; }
            }
        }
#pragma unroll
        for (int cg = 0; cg < COG; ++cg) {
#pragma unroll
            for (int dy = 0; dy < 5; ++dy) {
#pragma unroll
                for (int dx = 0; dx < 5; ++dx) {
                    float wv = ws[(cg * CI + ci) * 25 + dy * 5 + dx];
                    acc[cg][0] = fmaf(wv, p[dy][dx],     acc[cg][0]);
                    acc[cg][1] = fmaf(wv, p[dy][dx + 1], acc[cg][1]);
                }
            }
        }
    }

    int r = t / Wt;
    float m[COG];
#pragma unroll
    for (int cg = 0; cg < COG; ++cg) {
        float v0 = leaky(acc[cg][0]), v1 = leaky(acc[cg][1]);
        m[cg] = fmaxf(v0, v1);
        if (n >= 2) {
            float2 stv; stv.x = v0; stv.y = v1;
            *(float2*)(c2 + ((size_t)((n - 2) * CO + g * COG + cg)) * H * W + y * W + x0) = stv;
        }
    }
    if (r & 1) {
#pragma unroll
        for (int cg = 0; cg < COG; ++cg)
            pl[((r >> 1) * COG + cg) * Wt + col] = m[cg];
    }
    __syncthreads();
    if (!(r & 1)) {
#pragma unroll
        for (int cg = 0; cg < COG; ++cg) {
            float pv = fmaxf(m[cg], pl[((r >> 1) * COG + cg) * Wt + col]);
            pout[((size_t)(n * CO + g * COG + cg)) * Wt * Wt + (y >> 1) * Wt + col] = pv;
        }
    }
}

// ================= Attention: fused query gather + cosine similarity =================
template<int C, int RP, int SHIFT>
__global__ void __launch_bounds__(256) attn_k(
    const float* __restrict__ pool, const int* __restrict__ pts,
    float* __restrict__ out)
{
    constexpr int P = RP * RP;
    __shared__ float qs[32 * C];
    int t = threadIdx.x, b = blockIdx.y;
    if (t < 32) {
        int l = t;
        int py = pts[(b * 32 + l) * 2 + 0] >> SHIFT;
        int px = pts[(b * 32 + l) * 2 + 1] >> SHIFT;
        const float* qp = pool + (size_t)(b * C) * P + py * RP + px;
        float v[C]; float s = 0.f;
#pragma unroll
        for (int c = 0; c < C; ++c) { v[c] = qp[c * P]; s += v[c] * v[c]; }
        float invn = 1.f / fmaxf(sqrtf(s), 1e-8f);
#pragma unroll
        for (int c = 0; c < C; ++c) qs[l * C + c] = v[c] * invn;
    }
    __syncthreads();
    int p = blockIdx.x * 256 + t;
    const float* hp = pool + (size_t)((2 + b) * C) * P + p;
    float v[C]; float s = 0.f;
#pragma unroll
    for (int c = 0; c < C; ++c) { v[c] = hp[c * P]; s += v[c] * v[c]; }
    float invn2 = 1.f / fmaxf(sqrtf(s), 1e-8f);
#pragma unroll 4
    for (int l = 0; l < 32; ++l) {
        float d = 0.f;
#pragma unroll
        for (int c = 0; c < C; ++c) d = fmaf(v[c], qs[l * C + c], d);
        out[(size_t)(b * 32 + l) * P + p] = d * invn2;
    }
}

// ================= Decoder conv3x3 pad1, fused upsample+concat, 2x2 output tile ======
// (used for dec0/dec1 — small resolutions)
template<int R, int CP, int CF, int CO, int COG, bool TILEDPREV, bool DOLEAKY>
__global__ void __launch_bounds__(256) dec_k(
    const float* __restrict__ prev, const float* __restrict__ attn,
    const float* __restrict__ feat, const float* __restrict__ w,
    const float* __restrict__ bias, float* __restrict__ out)
{
    constexpr int CIN = CP + 1 + CF, Rh = R / 2;
    __shared__ float ws[COG * CIN * 9];
    int t = threadIdx.x, gid = blockIdx.x * 256 + t;
    int tx = gid % Rh;
    int ty = (gid / Rh) % Rh;
    int k = (gid / (Rh * Rh)) & 63;
    int g = gid / (Rh * Rh * 64);

    for (int i = t; i < COG * CIN * 9; i += 256) ws[i] = w[g * COG * CIN * 9 + i];
    __syncthreads();

    float acc[COG][2][2];
#pragma unroll
    for (int cg = 0; cg < COG; ++cg) {
        float b0 = bias[g * COG + cg];
        acc[cg][0][0] = b0; acc[cg][0][1] = b0; acc[cg][1][0] = b0; acc[cg][1][1] = b0;
    }

    bool hr[3], hc[3], fr[4], fc[4];
#pragma unroll
    for (int i = 0; i < 3; ++i) {
        int yy = ty - 1 + i; hr[i] = (yy >= 0) && (yy < Rh);
        int xx = tx - 1 + i; hc[i] = (xx >= 0) && (xx < Rh);
    }
#pragma unroll
    for (int i = 0; i < 4; ++i) {
        int yy = 2 * ty - 1 + i; fr[i] = (yy >= 0) && (yy < R);
        int xx = 2 * tx - 1 + i; fc[i] = (xx >= 0) && (xx < R);
    }

    constexpr int HM0[3] = {0, 1, 1};
    constexpr int HM1[3] = {1, 1, 2};

    int np = TILEDPREV ? (2 + (k & 1)) : k;
    int kf = k & 1;

    for (int ci = 0; ci < CP + 1; ++ci) {
        const float* bp = (ci < CP) ? (prev + ((size_t)(np * CP + ci)) * Rh * Rh)
                                    : (attn + (size_t)k * Rh * Rh);
        bp += (ty - 1) * Rh + (tx - 1);
        float P[3][3];
#pragma unroll
        for (int i = 0; i < 3; ++i)
#pragma unroll
            for (int j = 0; j < 3; ++j)
                P[i][j] = (hr[i] & hc[j]) ? bp[i * Rh + j] : 0.f;
#pragma unroll
        for (int cg = 0; cg < COG; ++cg) {
#pragma unroll
            for (int dy = 0; dy < 3; ++dy) {
#pragma unroll
                for (int dx = 0; dx < 3; ++dx) {
                    float wv = ws[(cg * CIN + ci) * 9 + dy * 3 + dx];
                    acc[cg][0][0] = fmaf(wv, P[HM0[dy]][HM0[dx]], acc[cg][0][0]);
                    acc[cg][0][1] = fmaf(wv, P[HM0[dy]][HM1[dx]], acc[cg][0][1]);
                    acc[cg][1][0] = fmaf(wv, P[HM1[dy]][HM0[dx]], acc[cg][1][0]);
                    acc[cg][1][1] = fmaf(wv, P[HM1[dy]][HM1[dx]], acc[cg][1][1]);
                }
            }
        }
    }

    for (int cf = 0; cf < CF; ++cf) {
        const float* bp = feat + ((size_t)(kf * CF + cf)) * R * R + (2 * ty - 1) * R + (2 * tx - 1);
        float F[4][4];
#pragma unroll
        for (int i = 0; i < 4; ++i)
#pragma unroll
            for (int j = 0; j < 4; ++j)
                F[i][j] = (fr[i] & fc[j]) ? bp[i * R + j] : 0.f;
#pragma unroll
        for (int cg = 0; cg < COG; ++cg) {
#pragma unroll
            for (int dy = 0; dy < 3; ++dy) {
#pragma unroll
                for (int dx = 0; dx < 3; ++dx) {
                    float wv = ws[(cg * CIN + CP + 1 + cf) * 9 + dy * 3 + dx];
                    acc[cg][0][0] = fmaf(wv, F[dy][dx],         acc[cg][0][0]);
                    acc[cg][0][1] = fmaf(wv, F[dy][dx + 1],     acc[cg][0][1]);
                    acc[cg][1][0] = fmaf(wv, F[dy + 1][dx],     acc[cg][1][0]);
                    acc[cg][1][1] = fmaf(wv, F[dy + 1][dx + 1], acc[cg][1][1]);
                }
            }
        }
    }

#pragma unroll
    for (int cg = 0; cg < COG; ++cg) {
        float v00 = acc[cg][0][0], v01 = acc[cg][0][1];
        float v10 = acc[cg][1][0], v11 = acc[cg][1][1];
        if (DOLEAKY) { v00 = leaky(v00); v01 = leaky(v01); v10 = leaky(v10); v11 = leaky(v11); }
        float* op = out + ((size_t)(k * CO + g * COG + cg)) * R * R + (2 * ty) * R + 2 * tx;
        float2 a; a.x = v00; a.y = v01; *(float2*)op = a;
        float2 b2; b2.x = v10; b2.y = v11; *(float2*)(op + R) = b2;
    }
}

// ================= Decoder, LDS-staged: one block = one (k, 32x32 tile) ==============
// Stage half-res halo patches (CP+1 planes, 18x18) and full-res feat (CF planes, 34x34)
// into LDS with coalesced, bounds-checked loads; then 2x2 px/thread from LDS with
// zero bounds checks in the FMA loops.
template<int R, int CP, int CF, int CO, bool DOLEAKY>
__global__ void __launch_bounds__(256) dec_staged_k(
    const float* __restrict__ prev, const float* __restrict__ attn,
    const float* __restrict__ feat, const float* __restrict__ w,
    const float* __restrict__ bias, float* __restrict__ out)
{
    constexpr int CIN = CP + 1 + CF, Rh = R / 2, TILES = R / 32;
    constexpr int NH = (CP + 1) * 18 * 18;
    constexpr int NF = CF * 34 * 34;
    __shared__ float sh[NH];
    __shared__ float sf[NF];
    __shared__ float ws[CO * CIN * 9];
    __shared__ float bs[CO];

    int t = threadIdx.x;
    int k = blockIdx.y;
    int tileY = blockIdx.x / TILES, tileX = blockIdx.x % TILES;
    int Y0 = 32 * tileY, X0 = 32 * tileX;
    int A0 = 16 * tileY, B0 = 16 * tileX;
    int kf = k & 1;

    for (int i = t; i < CO * CIN * 9; i += 256) ws[i] = w[i];
    if (t < CO) bs[t] = bias[t];

    // stage half-res planes (prev CP, then attn), origin (A0-1, B0-1), 18x18 each
    for (int i = t; i < NH; i += 256) {
        int c = i / 324; int rem = i - c * 324;
        int r = rem / 18, col = rem - r * 18;
        int gy = A0 - 1 + r, gx = B0 - 1 + col;
        const float* pl = (c < CP) ? prev + ((size_t)(k * CP + c)) * Rh * Rh
                                   : attn + (size_t)k * Rh * Rh;
        sh[i] = (gy >= 0 && gy < Rh && gx >= 0 && gx < Rh) ? pl[gy * Rh + gx] : 0.f;
    }
    // stage full-res feat planes, origin (Y0-1, X0-1), 34x34 each
    for (int i = t; i < NF; i += 256) {
        int c = i / 1156; int rem = i - c * 1156;
        int r = rem / 34, col = rem - r * 34;
        int gy = Y0 - 1 + r, gx = X0 - 1 + col;
        const float* pl = feat + ((size_t)(kf * CF + c)) * R * R;
        sf[i] = (gy >= 0 && gy < R && gx >= 0 && gx < R) ? pl[gy * R + gx] : 0.f;
    }
    __syncthreads();

    int px = t & 15, py = t >> 4;

    float acc[CO][2][2];
#pragma unroll
    for (int co = 0; co < CO; ++co) {
        float b0 = bs[co];
        acc[co][0][0] = b0; acc[co][0][1] = b0; acc[co][1][0] = b0; acc[co][1][1] = b0;
    }

    constexpr int HM0[3] = {0, 1, 1};
    constexpr int HM1[3] = {1, 1, 2};

    // half-res channels (prev, then attn): 3x3 register patch from LDS
    for (int ci = 0; ci < CP + 1; ++ci) {
        const float* shp = sh + ci * 324 + py * 18 + px;
        float P[3][3];
#pragma unroll
        for (int i = 0; i < 3; ++i)
#pragma unroll
            for (int j = 0; j < 3; ++j)
                P[i][j] = shp[i * 18 + j];
#pragma unroll
        for (int co = 0; co < CO; ++co) {
#pragma unroll
            for (int dy = 0; dy < 3; ++dy) {
#pragma unroll
                for (int dx = 0; dx < 3; ++dx) {
                    float wv = ws[(co * CIN + ci) * 9 + dy * 3 + dx];
                    acc[co][0][0] = fmaf(wv, P[HM0[dy]][HM0[dx]], acc[co][0][0]);
                    acc[co][0][1] = fmaf(wv, P[HM0[dy]][HM1[dx]], acc[co][0][1]);
                    acc[co][1][0] = fmaf(wv, P[HM1[dy]][HM0[dx]], acc[co][1][0]);
                    acc[co][1][1] = fmaf(wv, P[HM1[dy]][HM1[dx]], acc[co][1][1]);
                }
            }
        }
    }

    // full-res feat channels: 4x4 register patch from LDS
    for (int cf = 0; cf < CF; ++cf) {
        const float* sfp = sf + cf * 1156 + (2 * py) * 34 + 2 * px;
        float F[4][4];
#pragma unroll
        for (int i = 0; i < 4; ++i)
#pragma unroll
            for (int j = 0; j < 4; ++j)
                F[i][j] = sfp[i * 34 + j];
#pragma unroll
        for (int co = 0; co < CO; ++co) {
#pragma unroll
            for (int dy = 0; dy < 3; ++dy) {
#pragma unroll
                for (int dx = 0; dx < 3; ++dx) {
                    float wv = ws[(co * CIN + CP + 1 + cf) * 9 + dy * 3 + dx];
                    acc[co][0][0] = fmaf(wv, F[dy][dx],         acc[co][0][0]);
                    acc[co][0][1] = fmaf(wv, F[dy][dx + 1],     acc[co][0][1]);
                    acc[co][1][0] = fmaf(wv, F[dy + 1][dx],     acc[co][1][0]);
                    acc[co][1][1] = fmaf(wv, F[dy + 1][dx + 1], acc[co][1][1]);
                }
            }
        }
    }

#pragma unroll
    for (int co = 0; co < CO; ++co) {
        float v00 = acc[co][0][0], v01 = acc[co][0][1];
        float v10 = acc[co][1][0], v11 = acc[co][1][1];
        if (DOLEAKY) { v00 = leaky(v00); v01 = leaky(v01); v10 = leaky(v10); v11 = leaky(v11); }
        float* op = out + ((size_t)(k * CO + co)) * R * R + (Y0 + 2 * py) * R + X0 + 2 * px;
        float2 a; a.x = v00; a.y = v01; *(float2*)op = a;
        float2 b2; b2.x = v10; b2.y = v11; *(float2*)(op + R) = b2;
    }
}

extern "C" void kernel_launch(void* const* d_in, const int* in_sizes, int n_in,
                              void* d_out, int out_size, void* d_ws, size_t ws_size,
                              hipStream_t stream)
{
    (void)in_sizes; (void)n_in; (void)out_size; (void)ws_size;
    const float* x1 = (const float*)d_in[0];
    const float* x2 = (const float*)d_in[1];
    const int* pts = (const int*)d_in[2];
    const float* ew[4] = {(const float*)d_in[3], (const float*)d_in[5],
                          (const float*)d_in[7], (const float*)d_in[9]};
    const float* eb[4] = {(const float*)d_in[4], (const float*)d_in[6],
                          (const float*)d_in[8], (const float*)d_in[10]};
    const float* dw[4] = {(const float*)d_in[11], (const float*)d_in[13],
                          (const float*)d_in[15], (const float*)d_in[17]};
    const float* db[4] = {(const float*)d_in[12], (const float*)d_in[14],
                          (const float*)d_in[16], (const float*)d_in[18]};

    float* wsp = (float*)d_ws;
    size_t off = 0;
    auto A = [&](size_t n) { float* p = wsp + off; off += n; return p; };

    // pooled activations, all 4 virtual images: [4][C][Rp][Rp]
    float* p0 = A((size_t)4 * 4 * 128 * 128);
    float* p1 = A((size_t)4 * 8 * 64 * 64);
    float* p2 = A((size_t)4 * 16 * 32 * 32);
    float* p3 = A((size_t)4 * 16 * 16 * 16);
    // pre-pool conv outputs, image-2 only: [2][C][R][R]
    float* c2_0 = A((size_t)2 * 4 * 256 * 256);
    float* c2_1 = A((size_t)2 * 8 * 128 * 128);
    float* c2_2 = A((size_t)2 * 16 * 64 * 64);
    float* c2_3 = A((size_t)2 * 16 * 32 * 32);
    // attention maps [64][Rp][Rp]
    float* at0 = A((size_t)64 * 128 * 128);
    float* at1 = A((size_t)64 * 64 * 64);
    float* at2 = A((size_t)64 * 32 * 32);
    float* at3 = A((size_t)64 * 16 * 16);
    // decoder intermediates
    float* dec0 = A((size_t)64 * 16 * 32 * 32);
    float* dec1 = A((size_t)64 * 8 * 64 * 64);
    float* dec2 = A((size_t)64 * 4 * 128 * 128);
    float* outp = (float*)d_out;

    // ---- Encoder (4 virtual images per launch, conv+leaky+pool fused) ----
    enc_k<256, 3, 4, 2><<<1024, 256, 0, stream>>>(x1, x2, ew[0], eb[0], c2_0, p0);
    enc_k<128, 4, 8, 2><<<512, 256, 0, stream>>>(p0, p0 + (size_t)2 * 4 * 128 * 128,
                                                 ew[1], eb[1], c2_1, p1);
    enc_k<64, 8, 16, 2><<<256, 256, 0, stream>>>(p1, p1 + (size_t)2 * 8 * 64 * 64,
                                                 ew[2], eb[2], c2_2, p2);
    enc_k<32, 16, 16, 1><<<128, 256, 0, stream>>>(p2, p2 + (size_t)2 * 16 * 32 * 32,
                                                  ew[3], eb[3], c2_3, p3);

    // ---- Attention (query gather fused) ----
    { dim3 g(64, 2); attn_k<4, 128, 1><<<g, 256, 0, stream>>>(p0, pts, at0); }
    { dim3 g(16, 2); attn_k<8, 64, 2><<<g, 256, 0, stream>>>(p1, pts, at1); }
    { dim3 g(4, 2);  attn_k<16, 32, 3><<<g, 256, 0, stream>>>(p2, pts, at2); }
    { dim3 g(1, 2);  attn_k<16, 16, 4><<<g, 256, 0, stream>>>(p3, pts, at3); }

    // ---- Decoder (fused upsample+concat) ----
    // dec0: 2x2 tiles, COG=8 (2 groups)
    dec_k<32, 16, 16, 16, 8, true, true><<<128, 256, 0, stream>>>(p3, at3, c2_3, dw[0], db[0], dec0);
    // dec1: 2x2 tiles, COG=8 (1 group)
    dec_k<64, 16, 16, 8, 8, false, true><<<256, 256, 0, stream>>>(dec0, at2, c2_2, dw[1], db[1], dec1);
    // dec2: LDS-staged, 16 tiles x 64 k
    { dim3 g(16, 64); dec_staged_k<128, 8, 8, 4, true><<<g, 256, 0, stream>>>(dec1, at1, c2_1, dw[2], db[2], dec2); }
    // dec3: LDS-staged, 64 tiles x 64 k
    { dim3 g(64, 64); dec_staged_k<256, 4, 4, 1, false><<<g, 256, 0, stream>>>(dec2, at0, c2_0, dw[3], db[3], outp); }
}

// Round 5
// 213.044 us; speedup vs baseline: 1.0679x; 1.0679x over previous
//
#include <hip/hip_runtime.h>
#include <cstdint>

__device__ __forceinline__ float leaky(float v) { return v >= 0.f ? v : 0.01f * v; }

// ================= Encoder level 0: staged conv5x5 + leaky + pool ====================
// Block = (n, 32x32 conv tile). Thread = 2x2 pool-aligned quad. LDS: 3 x 36x36 src.
__global__ void __launch_bounds__(256) enc0_k(
    const float* __restrict__ x1, const float* __restrict__ x2,
    const float* __restrict__ w, const float* __restrict__ bias,
    float* __restrict__ c2, float* __restrict__ pout)
{
    constexpr int R = 256;
    __shared__ float ss[3 * 36 * 36];
    __shared__ float ws[4 * 3 * 25 + 4];
    int t = threadIdx.x;
    int n = blockIdx.y;
    int tileY = blockIdx.x >> 3, tileX = blockIdx.x & 7;
    int Y0 = 32 * tileY, X0 = 32 * tileX;
    const float* src = (n < 2) ? x1 + (size_t)n * 3 * R * R
                               : x2 + (size_t)(n - 2) * 3 * R * R;

    for (int i = t; i < 300; i += 256) ws[i] = w[i];
    if (t < 4) ws[300 + t] = bias[t];
    for (int ci = 0; ci < 3; ++ci) {
        const float* sp = src + (size_t)ci * R * R;
        for (int i = t; i < 1296; i += 256) {
            int r = i / 36, col = i - r * 36;
            int gy = Y0 - 2 + r, gx = X0 - 2 + col;
            float v = 0.f;
            if (gy >= 0 && gy < R && gx >= 0 && gx < R) v = sp[gy * R + gx];
            ss[ci * 1296 + i] = v;
        }
    }
    __syncthreads();

    int qx = t & 15, qy = t >> 4;
    float acc[4][2][2];
#pragma unroll
    for (int co = 0; co < 4; ++co) {
        float b0 = ws[300 + co];
        acc[co][0][0] = b0; acc[co][0][1] = b0; acc[co][1][0] = b0; acc[co][1][1] = b0;
    }
#pragma unroll
    for (int ci = 0; ci < 3; ++ci) {
        const float* sp = &ss[ci * 1296 + (2 * qy) * 36 + 2 * qx];
        float S[6][6];
#pragma unroll
        for (int i = 0; i < 6; ++i)
#pragma unroll
            for (int j = 0; j < 6; ++j) S[i][j] = sp[i * 36 + j];
#pragma unroll
        for (int co = 0; co < 4; ++co) {
#pragma unroll
            for (int dy = 0; dy < 5; ++dy) {
#pragma unroll
                for (int dx = 0; dx < 5; ++dx) {
                    float wv = ws[(co * 3 + ci) * 25 + dy * 5 + dx];
                    acc[co][0][0] = fmaf(wv, S[dy][dx],         acc[co][0][0]);
                    acc[co][0][1] = fmaf(wv, S[dy][dx + 1],     acc[co][0][1]);
                    acc[co][1][0] = fmaf(wv, S[dy + 1][dx],     acc[co][1][0]);
                    acc[co][1][1] = fmaf(wv, S[dy + 1][dx + 1], acc[co][1][1]);
                }
            }
        }
    }
#pragma unroll
    for (int co = 0; co < 4; ++co) {
        float v00 = leaky(acc[co][0][0]), v01 = leaky(acc[co][0][1]);
        float v10 = leaky(acc[co][1][0]), v11 = leaky(acc[co][1][1]);
        if (n >= 2) {
            float* op = c2 + ((size_t)((n - 2) * 4 + co)) * R * R + (Y0 + 2 * qy) * R + X0 + 2 * qx;
            float2 a; a.x = v00; a.y = v01; *(float2*)op = a;
            float2 b2; b2.x = v10; b2.y = v11; *(float2*)(op + R) = b2;
        }
        float pv = fmaxf(fmaxf(v00, v01), fmaxf(v10, v11));
        pout[((size_t)(n * 4 + co)) * 16384 + (16 * tileY + qy) * 128 + 16 * tileX + qx] = pv;
    }
}

// ================= Encoder: conv5x5 pad2 + leaky + fused 2x2 maxpool (levels 1-3) ====
template<int R, int CI, int CO, int COG>
__global__ void __launch_bounds__(256) enc_k(
    const float* __restrict__ src1, const float* __restrict__ src2,
    const float* __restrict__ w, const float* __restrict__ bias,
    float* __restrict__ c2, float* __restrict__ pout)
{
    constexpr int W = R, H = R, Wt = R / 2;
    constexpr int RPB = 256 / Wt;
    __shared__ float ws[COG * CI * 25];
    __shared__ float pl[(RPB / 2) * COG * Wt];

    int t = threadIdx.x;
    int gid = blockIdx.x * 256 + t;
    int col = gid % Wt;
    int y = (gid / Wt) % H;
    int n = (gid / (Wt * H)) & 3;
    int g = gid / (Wt * H * 4);

    for (int i = t; i < COG * CI * 25; i += 256) ws[i] = w[g * COG * CI * 25 + i];
    __syncthreads();

    const float* sp = (n < 2) ? (src1 + (size_t)n * CI * H * W)
                              : (src2 + (size_t)(n - 2) * CI * H * W);
    int x0 = col * 2;

    float acc[COG][2];
#pragma unroll
    for (int cg = 0; cg < COG; ++cg) { float b0 = bias[g * COG + cg]; acc[cg][0] = b0; acc[cg][1] = b0; }

    bool okr[5], okc[3];
#pragma unroll
    for (int i = 0; i < 5; ++i) { int yy = y + i - 2; okr[i] = (yy >= 0) && (yy < H); }
#pragma unroll
    for (int j = 0; j < 3; ++j) { int xx = x0 + 2 * j - 2; okc[j] = (xx >= 0) && (xx < W); }

    for (int ci = 0; ci < CI; ++ci) {
        const float* s = sp + ci * H * W + (y - 2) * W + (x0 - 2);
        float p[5][6];
#pragma unroll
        for (int i = 0; i < 5; ++i) {
#pragma unroll
            for (int j = 0; j < 3; ++j) {
                if (okr[i] & okc[j]) {
                    float2 v = *(const float2*)(s + i * W + 2 * j);
                    p[i][2 * j] = v.x; p[i][2 * j + 1] = v.y;
                } else { p[i][2 * j] = 0.f; p[i][2 * j + 1] = 0.f; }
            }
        }
#pragma unroll
        for (int cg = 0; cg < COG; ++cg) {
#pragma unroll
            for (int dy = 0; dy < 5; ++dy) {
#pragma unroll
                for (int dx = 0; dx < 5; ++dx) {
                    float wv = ws[(cg * CI + ci) * 25 + dy * 5 + dx];
                    acc[cg][0] = fmaf(wv, p[dy][dx],     acc[cg][0]);
                    acc[cg][1] = fmaf(wv, p[dy][dx + 1], acc[cg][1]);
                }
            }
        }
    }

    int r = t / Wt;
    float m[COG];
#pragma unroll
    for (int cg = 0; cg < COG; ++cg) {
        float v0 = leaky(acc[cg][0]), v1 = leaky(acc[cg][1]);
        m[cg] = fmaxf(v0, v1);
        if (n >= 2) {
            float2 stv; stv.x = v0; stv.y = v1;
            *(float2*)(c2 + ((size_t)((n - 2) * CO + g * COG + cg)) * H * W + y * W + x0) = stv;
        }
    }
    if (r & 1) {
#pragma unroll
        for (int cg = 0; cg < COG; ++cg)
            pl[((r >> 1) * COG + cg) * Wt + col] = m[cg];
    }
    __syncthreads();
    if (!(r & 1)) {
#pragma unroll
        for (int cg = 0; cg < COG; ++cg) {
            float pv = fmaxf(m[cg], pl[((r >> 1) * COG + cg) * Wt + col]);
            pout[((size_t)(n * CO + g * COG + cg)) * Wt * Wt + (y >> 1) * Wt + col] = pv;
        }
    }
}

// ================= Attention: fused query gather + cosine similarity =================
template<int C, int RP, int SHIFT>
__global__ void __launch_bounds__(256) attn_k(
    const float* __restrict__ pool, const int* __restrict__ pts,
    float* __restrict__ out)
{
    constexpr int P = RP * RP;
    __shared__ float qs[32 * C];
    int t = threadIdx.x, b = blockIdx.y;
    if (t < 32) {
        int l = t;
        int py = pts[(b * 32 + l) * 2 + 0] >> SHIFT;
        int px = pts[(b * 32 + l) * 2 + 1] >> SHIFT;
        const float* qp = pool + (size_t)(b * C) * P + py * RP + px;
        float v[C]; float s = 0.f;
#pragma unroll
        for (int c = 0; c < C; ++c) { v[c] = qp[c * P]; s += v[c] * v[c]; }
        float invn = 1.f / fmaxf(sqrtf(s), 1e-8f);
#pragma unroll
        for (int c = 0; c < C; ++c) qs[l * C + c] = v[c] * invn;
    }
    __syncthreads();
    int p = blockIdx.x * 256 + t;
    const float* hp = pool + (size_t)((2 + b) * C) * P + p;
    float v[C]; float s = 0.f;
#pragma unroll
    for (int c = 0; c < C; ++c) { v[c] = hp[c * P]; s += v[c] * v[c]; }
    float invn2 = 1.f / fmaxf(sqrtf(s), 1e-8f);
#pragma unroll 4
    for (int l = 0; l < 32; ++l) {
        float d = 0.f;
#pragma unroll
        for (int c = 0; c < C; ++c) d = fmaf(v[c], qs[l * C + c], d);
        out[(size_t)(b * 32 + l) * P + p] = d * invn2;
    }
}

// ================= dec0: conv3x3 fused upsample+concat, 2x2 tile (unstaged) ==========
template<int R, int CP, int CF, int CO, int COG, bool TILEDPREV, bool DOLEAKY>
__global__ void __launch_bounds__(256) dec_k(
    const float* __restrict__ prev, const float* __restrict__ attn,
    const float* __restrict__ feat, const float* __restrict__ w,
    const float* __restrict__ bias, float* __restrict__ out)
{
    constexpr int CIN = CP + 1 + CF, Rh = R / 2;
    __shared__ float ws[COG * CIN * 9];
    int t = threadIdx.x, gid = blockIdx.x * 256 + t;
    int tx = gid % Rh;
    int ty = (gid / Rh) % Rh;
    int k = (gid / (Rh * Rh)) & 63;
    int g = gid / (Rh * Rh * 64);

    for (int i = t; i < COG * CIN * 9; i += 256) ws[i] = w[g * COG * CIN * 9 + i];
    __syncthreads();

    float acc[COG][2][2];
#pragma unroll
    for (int cg = 0; cg < COG; ++cg) {
        float b0 = bias[g * COG + cg];
        acc[cg][0][0] = b0; acc[cg][0][1] = b0; acc[cg][1][0] = b0; acc[cg][1][1] = b0;
    }

    bool hr[3], hc[3], fr[4], fc[4];
#pragma unroll
    for (int i = 0; i < 3; ++i) {
        int yy = ty - 1 + i; hr[i] = (yy >= 0) && (yy < Rh);
        int xx = tx - 1 + i; hc[i] = (xx >= 0) && (xx < Rh);
    }
#pragma unroll
    for (int i = 0; i < 4; ++i) {
        int yy = 2 * ty - 1 + i; fr[i] = (yy >= 0) && (yy < R);
        int xx = 2 * tx - 1 + i; fc[i] = (xx >= 0) && (xx < R);
    }

    constexpr int HM0[3] = {0, 1, 1};
    constexpr int HM1[3] = {1, 1, 2};

    int np = TILEDPREV ? (2 + (k & 1)) : k;
    int kf = k & 1;

    for (int ci = 0; ci < CP + 1; ++ci) {
        const float* bp = (ci < CP) ? (prev + ((size_t)(np * CP + ci)) * Rh * Rh)
                                    : (attn + (size_t)k * Rh * Rh);
        bp += (ty - 1) * Rh + (tx - 1);
        float P[3][3];
#pragma unroll
        for (int i = 0; i < 3; ++i)
#pragma unroll
            for (int j = 0; j < 3; ++j)
                P[i][j] = (hr[i] & hc[j]) ? bp[i * Rh + j] : 0.f;
#pragma unroll
        for (int cg = 0; cg < COG; ++cg) {
#pragma unroll
            for (int dy = 0; dy < 3; ++dy) {
#pragma unroll
                for (int dx = 0; dx < 3; ++dx) {
                    float wv = ws[(cg * CIN + ci) * 9 + dy * 3 + dx];
                    acc[cg][0][0] = fmaf(wv, P[HM0[dy]][HM0[dx]], acc[cg][0][0]);
                    acc[cg][0][1] = fmaf(wv, P[HM0[dy]][HM1[dx]], acc[cg][0][1]);
                    acc[cg][1][0] = fmaf(wv, P[HM1[dy]][HM0[dx]], acc[cg][1][0]);
                    acc[cg][1][1] = fmaf(wv, P[HM1[dy]][HM1[dx]], acc[cg][1][1]);
                }
            }
        }
    }

    for (int cf = 0; cf < CF; ++cf) {
        const float* bp = feat + ((size_t)(kf * CF + cf)) * R * R + (2 * ty - 1) * R + (2 * tx - 1);
        float F[4][4];
#pragma unroll
        for (int i = 0; i < 4; ++i)
#pragma unroll
            for (int j = 0; j < 4; ++j)
                F[i][j] = (fr[i] & fc[j]) ? bp[i * R + j] : 0.f;
#pragma unroll
        for (int cg = 0; cg < COG; ++cg) {
#pragma unroll
            for (int dy = 0; dy < 3; ++dy) {
#pragma unroll
                for (int dx = 0; dx < 3; ++dx) {
                    float wv = ws[(cg * CIN + CP + 1 + cf) * 9 + dy * 3 + dx];
                    acc[cg][0][0] = fmaf(wv, F[dy][dx],         acc[cg][0][0]);
                    acc[cg][0][1] = fmaf(wv, F[dy][dx + 1],     acc[cg][0][1]);
                    acc[cg][1][0] = fmaf(wv, F[dy + 1][dx],     acc[cg][1][0]);
                    acc[cg][1][1] = fmaf(wv, F[dy + 1][dx + 1], acc[cg][1][1]);
                }
            }
        }
    }

#pragma unroll
    for (int cg = 0; cg < COG; ++cg) {
        float v00 = acc[cg][0][0], v01 = acc[cg][0][1];
        float v10 = acc[cg][1][0], v11 = acc[cg][1][1];
        if (DOLEAKY) { v00 = leaky(v00); v01 = leaky(v01); v10 = leaky(v10); v11 = leaky(v11); }
        float* op = out + ((size_t)(k * CO + g * COG + cg)) * R * R + (2 * ty) * R + 2 * tx;
        float2 a; a.x = v00; a.y = v01; *(float2*)op = a;
        float2 b2; b2.x = v10; b2.y = v11; *(float2*)(op + R) = b2;
    }
}

// ================= dec2/dec3: 4-k same-parity block, LDS staged, 2x2 quads ===========
// Block = (4 k sharing feat parity, 16x16 out tile). 256 thr = 4 ksub x 64 quads.
// LDS: feat CF x 18x18 (shared); per-k half planes (CP+1) x 10x10; weights.
template<int R, int CP, int CF, int CO, int MINW, bool DOLEAKY>
__global__ void __launch_bounds__(256, MINW) deckq_k(
    const float* __restrict__ prev, const float* __restrict__ attn,
    const float* __restrict__ feat, const float* __restrict__ w,
    const float* __restrict__ bias, float* __restrict__ out)
{
    constexpr int CIN = CP + 1 + CF, Rh = R / 2, TX = R / 16;
    __shared__ float sf[CF * 324];
    __shared__ float sh[4][(CP + 1) * 100];
    __shared__ float ws[CO * CIN * 9 + CO];

    int t = threadIdx.x;
    int kg = blockIdx.y;
    int p = kg & 1;
    int kbase = (kg >> 1) * 8 + p;          // k = kbase + 2*j, j=0..3
    int tileY = blockIdx.x / TX, tileX = blockIdx.x % TX;
    int Y0 = 16 * tileY, X0 = 16 * tileX;
    int hy0 = 8 * tileY - 1, hx0 = 8 * tileX - 1;

    for (int i = t; i < CO * CIN * 9; i += 256) ws[i] = w[i];
    if (t < CO) ws[CO * CIN * 9 + t] = bias[t];

    // feat (shared across the 4 k): 18x18, origin (Y0-1, X0-1)
    for (int i = t; i < CF * 324; i += 256) {
        int c = i / 324, rem = i - c * 324;
        int r = rem / 18, col = rem - r * 18;
        int gy = Y0 - 1 + r, gx = X0 - 1 + col;
        float v = 0.f;
        if (gy >= 0 && gy < R && gx >= 0 && gx < R)
            v = feat[((size_t)(p * CF + c)) * R * R + gy * R + gx];
        sf[i] = v;
    }
    // half-res prev planes: same geometry for all 4 k -> amortize addr math
    for (int i = t; i < CP * 100; i += 256) {
        int c = i / 100, rem = i - c * 100;
        int r = rem / 10, col = rem - r * 10;
        int gy = hy0 + r, gx = hx0 + col;
        bool ok = (gy >= 0) && (gy < Rh) && (gx >= 0) && (gx < Rh);
        int off = gy * Rh + gx;
#pragma unroll
        for (int j = 0; j < 4; ++j) {
            float v = 0.f;
            if (ok) v = prev[((size_t)((kbase + 2 * j) * CP + c)) * Rh * Rh + off];
            sh[j][i] = v;
        }
    }
    // attn plane per k
    if (t < 100) {
        int r = t / 10, col = t - r * 10;
        int gy = hy0 + r, gx = hx0 + col;
        bool ok = (gy >= 0) && (gy < Rh) && (gx >= 0) && (gx < Rh);
        int off = gy * Rh + gx;
#pragma unroll
        for (int j = 0; j < 4; ++j) {
            float v = 0.f;
            if (ok) v = attn[(size_t)(kbase + 2 * j) * Rh * Rh + off];
            sh[j][CP * 100 + t] = v;
        }
    }
    __syncthreads();

    int ksub = t >> 6, q = t & 63, qx = q & 7, qy = q >> 3;
    int k = kbase + 2 * ksub;

    float acc[CO][2][2];
#pragma unroll
    for (int co = 0; co < CO; ++co) {
        float b0 = ws[CO * CIN * 9 + co];
        acc[co][0][0] = b0; acc[co][0][1] = b0; acc[co][1][0] = b0; acc[co][1][1] = b0;
    }

    // half-res channels (prev, then attn): 3x3 register patch
#pragma unroll
    for (int ci = 0; ci < CP + 1; ++ci) {
        const float* hp = &sh[ksub][ci * 100 + qy * 10 + qx];
        float P[3][3];
#pragma unroll
        for (int i = 0; i < 3; ++i)
#pragma unroll
            for (int j = 0; j < 3; ++j) P[i][j] = hp[i * 10 + j];
#pragma unroll
        for (int co = 0; co < CO; ++co) {
#pragma unroll
            for (int dy = 0; dy < 3; ++dy) {
#pragma unroll
                for (int dx = 0; dx < 3; ++dx) {
                    float wv = ws[(co * CIN + ci) * 9 + dy * 3 + dx];
                    acc[co][0][0] = fmaf(wv, P[(0 + dy + 1) >> 1][(0 + dx + 1) >> 1], acc[co][0][0]);
                    acc[co][0][1] = fmaf(wv, P[(0 + dy + 1) >> 1][(1 + dx + 1) >> 1], acc[co][0][1]);
                    acc[co][1][0] = fmaf(wv, P[(1 + dy + 1) >> 1][(0 + dx + 1) >> 1], acc[co][1][0]);
                    acc[co][1][1] = fmaf(wv, P[(1 + dy + 1) >> 1][(1 + dx + 1) >> 1], acc[co][1][1]);
                }
            }
        }
    }
    // full-res feat channels: 4x4 register patch
#pragma unroll
    for (int cf = 0; cf < CF; ++cf) {
        const float* fp = &sf[cf * 324 + (2 * qy) * 18 + 2 * qx];
        float F[4][4];
#pragma unroll
        for (int i = 0; i < 4; ++i)
#pragma unroll
            for (int j = 0; j < 4; ++j) F[i][j] = fp[i * 18 + j];
#pragma unroll
        for (int co = 0; co < CO; ++co) {
#pragma unroll
            for (int dy = 0; dy < 3; ++dy) {
#pragma unroll
                for (int dx = 0; dx < 3; ++dx) {
                    float wv = ws[(co * CIN + CP + 1 + cf) * 9 + dy * 3 + dx];
                    acc[co][0][0] = fmaf(wv, F[0 + dy][0 + dx], acc[co][0][0]);
                    acc[co][0][1] = fmaf(wv, F[0 + dy][1 + dx], acc[co][0][1]);
                    acc[co][1][0] = fmaf(wv, F[1 + dy][0 + dx], acc[co][1][0]);
                    acc[co][1][1] = fmaf(wv, F[1 + dy][1 + dx], acc[co][1][1]);
                }
            }
        }
    }

#pragma unroll
    for (int co = 0; co < CO; ++co) {
        float v00 = acc[co][0][0], v01 = acc[co][0][1];
        float v10 = acc[co][1][0], v11 = acc[co][1][1];
        if (DOLEAKY) { v00 = leaky(v00); v01 = leaky(v01); v10 = leaky(v10); v11 = leaky(v11); }
        float* op = out + ((size_t)(k * CO + co)) * R * R + (Y0 + 2 * qy) * R + X0 + 2 * qx;
        float2 a; a.x = v00; a.y = v01; *(float2*)op = a;
        float2 b2; b2.x = v10; b2.y = v11; *(float2*)(op + R) = b2;
    }
}

// ================= dec1: 2-k same-parity block, co-group split, staged ===============
// Block = (2 k, co-group of 4, 16x16 tile). 256 thr = 2 ksub x (8 xpair x 16 rows).
// Half-res planes staged y-UPSAMPLED (18 rows x 10 cols) to kill runtime y-parity.
__global__ void __launch_bounds__(256, 4) dec1_k(
    const float* __restrict__ prev, const float* __restrict__ attn,
    const float* __restrict__ feat, const float* __restrict__ w,
    const float* __restrict__ bias, float* __restrict__ out)
{
    constexpr int R = 64, CP = 16, CF = 16, CIN = 33, Rh = 32;
    __shared__ float sf[CF * 324];
    __shared__ float shu[2][(CP + 1) * 180];
    __shared__ float ws[4 * CIN * 9 + 4];

    int t = threadIdx.x;
    int bz = blockIdx.y;               // 0..63
    int kg = bz >> 1, cog = bz & 1;
    int p = kg & 1;
    int kbase = (kg >> 1) * 4 + p;     // k = kbase + 2*j, j=0..1
    int tileY = blockIdx.x >> 2, tileX = blockIdx.x & 3;
    int Y0 = 16 * tileY, X0 = 16 * tileX;
    int hy0 = 8 * tileY - 1, hx0 = 8 * tileX - 1;

    for (int i = t; i < 4 * CIN * 9; i += 256) ws[i] = w[cog * 4 * CIN * 9 + i];
    if (t < 4) ws[4 * CIN * 9 + t] = bias[cog * 4 + t];

    for (int i = t; i < CF * 324; i += 256) {
        int c = i / 324, rem = i - c * 324;
        int r = rem / 18, col = rem - r * 18;
        int gy = Y0 - 1 + r, gx = X0 - 1 + col;
        float v = 0.f;
        if (gy >= 0 && gy < R && gx >= 0 && gx < R)
            v = feat[((size_t)(p * CF + c)) * R * R + gy * R + gx];
        sf[i] = v;
    }
    // y-upsampled half staging: LDS row q <-> half row hy0 + ((q+1)>>1)
    for (int i = t; i < CP * 180; i += 256) {
        int c = i / 180, rem = i - c * 180;
        int qr = rem / 10, col = rem - qr * 10;
        int gy = hy0 + ((qr + 1) >> 1), gx = hx0 + col;
        bool ok = (gy >= 0) && (gy < Rh) && (gx >= 0) && (gx < Rh);
        int off = gy * Rh + gx;
#pragma unroll
        for (int j = 0; j < 2; ++j) {
            float v = 0.f;
            if (ok) v = prev[((size_t)((kbase + 2 * j) * CP + c)) * Rh * Rh + off];
            shu[j][i] = v;
        }
    }
    if (t < 180) {
        int qr = t / 10, col = t - qr * 10;
        int gy = hy0 + ((qr + 1) >> 1), gx = hx0 + col;
        bool ok = (gy >= 0) && (gy < Rh) && (gx >= 0) && (gx < Rh);
        int off = gy * Rh + gx;
#pragma unroll
        for (int j = 0; j < 2; ++j) {
            float v = 0.f;
            if (ok) v = attn[(size_t)(kbase + 2 * j) * Rh * Rh + off];
            shu[j][CP * 180 + t] = v;
        }
    }
    __syncthreads();

    int ksub = t >> 7, r = t & 127, px = r & 7, py = r >> 3;
    int k = kbase + 2 * ksub;

    float acc[4][2];
#pragma unroll
    for (int co = 0; co < 4; ++co) {
        float b0 = ws[4 * CIN * 9 + co];
        acc[co][0] = b0; acc[co][1] = b0;
    }

#pragma unroll
    for (int ci = 0; ci < CP + 1; ++ci) {
        const float* hp = &shu[ksub][ci * 180 + py * 10 + px];
        float P[3][3];
#pragma unroll
        for (int i = 0; i < 3; ++i)
#pragma unroll
            for (int j = 0; j < 3; ++j) P[i][j] = hp[i * 10 + j];
#pragma unroll
        for (int co = 0; co < 4; ++co) {
#pragma unroll
            for (int dy = 0; dy < 3; ++dy) {
#pragma unroll
                for (int dx = 0; dx < 3; ++dx) {
                    float wv = ws[(co * CIN + ci) * 9 + dy * 3 + dx];
                    acc[co][0] = fmaf(wv, P[dy][(0 + dx + 1) >> 1], acc[co][0]);
                    acc[co][1] = fmaf(wv, P[dy][(1 + dx + 1) >> 1], acc[co][1]);
                }
            }
        }
    }
#pragma unroll
    for (int cf = 0; cf < CF; ++cf) {
        const float* fp = &sf[cf * 324 + py * 18 + 2 * px];
        float F[3][4];
#pragma unroll
        for (int i = 0; i < 3; ++i)
#pragma unroll
            for (int j = 0; j < 4; ++j) F[i][j] = fp[i * 18 + j];
#pragma unroll
        for (int co = 0; co < 4; ++co) {
#pragma unroll
            for (int dy = 0; dy < 3; ++dy) {
#pragma unroll
                for (int dx = 0; dx < 3; ++dx) {
                    float wv = ws[(co * CIN + CP + 1 + cf) * 9 + dy * 3 + dx];
                    acc[co][0] = fmaf(wv, F[dy][0 + dx], acc[co][0]);
                    acc[co][1] = fmaf(wv, F[dy][1 + dx], acc[co][1]);
                }
            }
        }
    }

#pragma unroll
    for (int co = 0; co < 4; ++co) {
        float v0 = leaky(acc[co][0]), v1 = leaky(acc[co][1]);
        float* op = out + ((size_t)(k * 8 + cog * 4 + co)) * R * R + (Y0 + py) * R + X0 + 2 * px;
        float2 a; a.x = v0; a.y = v1; *(float2*)op = a;
    }
}

extern "C" void kernel_launch(void* const* d_in, const int* in_sizes, int n_in,
                              void* d_out, int out_size, void* d_ws, size_t ws_size,
                              hipStream_t stream)
{
    (void)in_sizes; (void)n_in; (void)out_size; (void)ws_size;
    const float* x1 = (const float*)d_in[0];
    const float* x2 = (const float*)d_in[1];
    const int* pts = (const int*)d_in[2];
    const float* ew[4] = {(const float*)d_in[3], (const float*)d_in[5],
                          (const float*)d_in[7], (const float*)d_in[9]};
    const float* eb[4] = {(const float*)d_in[4], (const float*)d_in[6],
                          (const float*)d_in[8], (const float*)d_in[10]};
    const float* dw[4] = {(const float*)d_in[11], (const float*)d_in[13],
                          (const float*)d_in[15], (const float*)d_in[17]};
    const float* db[4] = {(const float*)d_in[12], (const float*)d_in[14],
                          (const float*)d_in[16], (const float*)d_in[18]};

    float* wsp = (float*)d_ws;
    size_t off = 0;
    auto A = [&](size_t n) { float* p = wsp + off; off += n; return p; };

    float* p0 = A((size_t)4 * 4 * 128 * 128);
    float* p1 = A((size_t)4 * 8 * 64 * 64);
    float* p2 = A((size_t)4 * 16 * 32 * 32);
    float* p3 = A((size_t)4 * 16 * 16 * 16);
    float* c2_0 = A((size_t)2 * 4 * 256 * 256);
    float* c2_1 = A((size_t)2 * 8 * 128 * 128);
    float* c2_2 = A((size_t)2 * 16 * 64 * 64);
    float* c2_3 = A((size_t)2 * 16 * 32 * 32);
    float* at0 = A((size_t)64 * 128 * 128);
    float* at1 = A((size_t)64 * 64 * 64);
    float* at2 = A((size_t)64 * 32 * 32);
    float* at3 = A((size_t)64 * 16 * 16);
    float* dec0 = A((size_t)64 * 16 * 32 * 32);
    float* dec1 = A((size_t)64 * 8 * 64 * 64);
    float* dec2 = A((size_t)64 * 4 * 128 * 128);
    float* outp = (float*)d_out;

    // ---- Encoder ----
    { dim3 g(64, 4); enc0_k<<<g, 256, 0, stream>>>(x1, x2, ew[0], eb[0], c2_0, p0); }
    enc_k<128, 4, 8, 2><<<512, 256, 0, stream>>>(p0, p0 + (size_t)2 * 4 * 128 * 128,
                                                 ew[1], eb[1], c2_1, p1);
    enc_k<64, 8, 16, 2><<<256, 256, 0, stream>>>(p1, p1 + (size_t)2 * 8 * 64 * 64,
                                                 ew[2], eb[2], c2_2, p2);
    enc_k<32, 16, 16, 1><<<128, 256, 0, stream>>>(p2, p2 + (size_t)2 * 16 * 32 * 32,
                                                  ew[3], eb[3], c2_3, p3);

    // ---- Attention ----
    { dim3 g(64, 2); attn_k<4, 128, 1><<<g, 256, 0, stream>>>(p0, pts, at0); }
    { dim3 g(16, 2); attn_k<8, 64, 2><<<g, 256, 0, stream>>>(p1, pts, at1); }
    { dim3 g(4, 2);  attn_k<16, 32, 3><<<g, 256, 0, stream>>>(p2, pts, at2); }
    { dim3 g(1, 2);  attn_k<16, 16, 4><<<g, 256, 0, stream>>>(p3, pts, at3); }

    // ---- Decoder ----
    // dec0: unstaged 2x2, COG=4 (4 groups) -> 256 blocks
    dec_k<32, 16, 16, 16, 4, true, true><<<256, 256, 0, stream>>>(p3, at3, c2_3, dw[0], db[0], dec0);
    // dec1: staged, 2-k groups x 2 co-groups, 16 tiles -> (16, 64)
    { dim3 g(16, 64); dec1_k<<<g, 256, 0, stream>>>(dec0, at2, c2_2, dw[1], db[1], dec1); }
    // dec2: staged 4-k quads: 64 tiles x 16 k-groups
    { dim3 g(64, 16); deckq_k<128, 8, 8, 4, 4, true><<<g, 256, 0, stream>>>(dec1, at1, c2_1, dw[2], db[2], dec2); }
    // dec3: staged 4-k quads: 256 tiles x 16 k-groups
    { dim3 g(256, 16); deckq_k<256, 4, 4, 1, 5, false><<<g, 256, 0, stream>>>(dec2, at0, c2_0, dw[3], db[3], outp); }
}

// Round 6
// 196.417 us; speedup vs baseline: 1.1582x; 1.0847x over previous
//
#include <hip/hip_runtime.h>
#include <cstdint>

__device__ __forceinline__ float leaky(float v) { return v >= 0.f ? v : 0.01f * v; }

// ================= Encoder level 0: staged conv5x5 + leaky + pool ====================
__global__ void __launch_bounds__(256) enc0_k(
    const float* __restrict__ x1, const float* __restrict__ x2,
    const float* __restrict__ w, const float* __restrict__ bias,
    float* __restrict__ c2, float* __restrict__ pout)
{
    constexpr int R = 256;
    __shared__ float ss[3 * 36 * 36];
    __shared__ float ws[4 * 3 * 25 + 4];
    int t = threadIdx.x;
    int n = blockIdx.y;
    int tileY = blockIdx.x >> 3, tileX = blockIdx.x & 7;
    int Y0 = 32 * tileY, X0 = 32 * tileX;
    const float* src = (n < 2) ? x1 + (size_t)n * 3 * R * R
                               : x2 + (size_t)(n - 2) * 3 * R * R;

    for (int i = t; i < 300; i += 256) ws[i] = w[i];
    if (t < 4) ws[300 + t] = bias[t];
    for (int ci = 0; ci < 3; ++ci) {
        const float* sp = src + (size_t)ci * R * R;
        for (int i = t; i < 1296; i += 256) {
            int r = i / 36, col = i - r * 36;
            int gy = Y0 - 2 + r, gx = X0 - 2 + col;
            float v = 0.f;
            if (gy >= 0 && gy < R && gx >= 0 && gx < R) v = sp[gy * R + gx];
            ss[ci * 1296 + i] = v;
        }
    }
    __syncthreads();

    int qx = t & 15, qy = t >> 4;
    float acc[4][2][2];
#pragma unroll
    for (int co = 0; co < 4; ++co) {
        float b0 = ws[300 + co];
        acc[co][0][0] = b0; acc[co][0][1] = b0; acc[co][1][0] = b0; acc[co][1][1] = b0;
    }
#pragma unroll
    for (int ci = 0; ci < 3; ++ci) {
        const float* sp = &ss[ci * 1296 + (2 * qy) * 36 + 2 * qx];
        float S[6][6];
#pragma unroll
        for (int i = 0; i < 6; ++i)
#pragma unroll
            for (int j = 0; j < 6; ++j) S[i][j] = sp[i * 36 + j];
#pragma unroll
        for (int co = 0; co < 4; ++co) {
#pragma unroll
            for (int dy = 0; dy < 5; ++dy) {
#pragma unroll
                for (int dx = 0; dx < 5; ++dx) {
                    float wv = ws[(co * 3 + ci) * 25 + dy * 5 + dx];
                    acc[co][0][0] = fmaf(wv, S[dy][dx],         acc[co][0][0]);
                    acc[co][0][1] = fmaf(wv, S[dy][dx + 1],     acc[co][0][1]);
                    acc[co][1][0] = fmaf(wv, S[dy + 1][dx],     acc[co][1][0]);
                    acc[co][1][1] = fmaf(wv, S[dy + 1][dx + 1], acc[co][1][1]);
                }
            }
        }
    }
#pragma unroll
    for (int co = 0; co < 4; ++co) {
        float v00 = leaky(acc[co][0][0]), v01 = leaky(acc[co][0][1]);
        float v10 = leaky(acc[co][1][0]), v11 = leaky(acc[co][1][1]);
        if (n >= 2) {
            float* op = c2 + ((size_t)((n - 2) * 4 + co)) * R * R + (Y0 + 2 * qy) * R + X0 + 2 * qx;
            float2 a; a.x = v00; a.y = v01; *(float2*)op = a;
            float2 b2; b2.x = v10; b2.y = v11; *(float2*)(op + R) = b2;
        }
        float pv = fmaxf(fmaxf(v00, v01), fmaxf(v10, v11));
        pout[((size_t)(n * 4 + co)) * 16384 + (16 * tileY + qy) * 128 + 16 * tileX + qx] = pv;
    }
}

// ================= Encoder: conv5x5 pad2 + leaky + fused 2x2 maxpool (levels 1-3) ====
template<int R, int CI, int CO, int COG>
__global__ void __launch_bounds__(256) enc_k(
    const float* __restrict__ src1, const float* __restrict__ src2,
    const float* __restrict__ w, const float* __restrict__ bias,
    float* __restrict__ c2, float* __restrict__ pout)
{
    constexpr int W = R, H = R, Wt = R / 2;
    constexpr int RPB = 256 / Wt;
    __shared__ float ws[COG * CI * 25];
    __shared__ float pl[(RPB / 2) * COG * Wt];

    int t = threadIdx.x;
    int gid = blockIdx.x * 256 + t;
    int col = gid % Wt;
    int y = (gid / Wt) % H;
    int n = (gid / (Wt * H)) & 3;
    int g = gid / (Wt * H * 4);

    for (int i = t; i < COG * CI * 25; i += 256) ws[i] = w[g * COG * CI * 25 + i];
    __syncthreads();

    const float* sp = (n < 2) ? (src1 + (size_t)n * CI * H * W)
                              : (src2 + (size_t)(n - 2) * CI * H * W);
    int x0 = col * 2;

    float acc[COG][2];
#pragma unroll
    for (int cg = 0; cg < COG; ++cg) { float b0 = bias[g * COG + cg]; acc[cg][0] = b0; acc[cg][1] = b0; }

    bool okr[5], okc[3];
#pragma unroll
    for (int i = 0; i < 5; ++i) { int yy = y + i - 2; okr[i] = (yy >= 0) && (yy < H); }
#pragma unroll
    for (int j = 0; j < 3; ++j) { int xx = x0 + 2 * j - 2; okc[j] = (xx >= 0) && (xx < W); }

    for (int ci = 0; ci < CI; ++ci) {
        const float* s = sp + ci * H * W + (y - 2) * W + (x0 - 2);
        float p[5][6];
#pragma unroll
        for (int i = 0; i < 5; ++i) {
#pragma unroll
            for (int j = 0; j < 3; ++j) {
                if (okr[i] & okc[j]) {
                    float2 v = *(const float2*)(s + i * W + 2 * j);
                    p[i][2 * j] = v.x; p[i][2 * j + 1] = v.y;
                } else { p[i][2 * j] = 0.f; p[i][2 * j + 1] = 0.f; }
            }
        }
#pragma unroll
        for (int cg = 0; cg < COG; ++cg) {
#pragma unroll
            for (int dy = 0; dy < 5; ++dy) {
#pragma unroll
                for (int dx = 0; dx < 5; ++dx) {
                    float wv = ws[(cg * CI + ci) * 25 + dy * 5 + dx];
                    acc[cg][0] = fmaf(wv, p[dy][dx],     acc[cg][0]);
                    acc[cg][1] = fmaf(wv, p[dy][dx + 1], acc[cg][1]);
                }
            }
        }
    }

    int r = t / Wt;
    float m[COG];
#pragma unroll
    for (int cg = 0; cg < COG; ++cg) {
        float v0 = leaky(acc[cg][0]), v1 = leaky(acc[cg][1]);
        m[cg] = fmaxf(v0, v1);
        if (n >= 2) {
            float2 stv; stv.x = v0; stv.y = v1;
            *(float2*)(c2 + ((size_t)((n - 2) * CO + g * COG + cg)) * H * W + y * W + x0) = stv;
        }
    }
    if (r & 1) {
#pragma unroll
        for (int cg = 0; cg < COG; ++cg)
            pl[((r >> 1) * COG + cg) * Wt + col] = m[cg];
    }
    __syncthreads();
    if (!(r & 1)) {
#pragma unroll
        for (int cg = 0; cg < COG; ++cg) {
            float pv = fmaxf(m[cg], pl[((r >> 1) * COG + cg) * Wt + col]);
            pout[((size_t)(n * CO + g * COG + cg)) * Wt * Wt + (y >> 1) * Wt + col] = pv;
        }
    }
}

// ================= Attention: fused query gather + cosine similarity =================
template<int C, int RP, int SHIFT>
__global__ void __launch_bounds__(256) attn_k(
    const float* __restrict__ pool, const int* __restrict__ pts,
    float* __restrict__ out)
{
    constexpr int P = RP * RP;
    __shared__ float qs[32 * C];
    int t = threadIdx.x, b = blockIdx.y;
    if (t < 32) {
        int l = t;
        int py = pts[(b * 32 + l) * 2 + 0] >> SHIFT;
        int px = pts[(b * 32 + l) * 2 + 1] >> SHIFT;
        const float* qp = pool + (size_t)(b * C) * P + py * RP + px;
        float v[C]; float s = 0.f;
#pragma unroll
        for (int c = 0; c < C; ++c) { v[c] = qp[c * P]; s += v[c] * v[c]; }
        float invn = 1.f / fmaxf(sqrtf(s), 1e-8f);
#pragma unroll
        for (int c = 0; c < C; ++c) qs[l * C + c] = v[c] * invn;
    }
    __syncthreads();
    int p = blockIdx.x * 256 + t;
    const float* hp = pool + (size_t)((2 + b) * C) * P + p;
    float v[C]; float s = 0.f;
#pragma unroll
    for (int c = 0; c < C; ++c) { v[c] = hp[c * P]; s += v[c] * v[c]; }
    float invn2 = 1.f / fmaxf(sqrtf(s), 1e-8f);
#pragma unroll 4
    for (int l = 0; l < 32; ++l) {
        float d = 0.f;
#pragma unroll
        for (int c = 0; c < C; ++c) d = fmaf(v[c], qs[l * C + c], d);
        out[(size_t)(b * 32 + l) * P + p] = d * invn2;
    }
}

// ================= dec0: conv3x3 fused upsample+concat, 2x2 tile (unstaged) ==========
template<int R, int CP, int CF, int CO, int COG, bool TILEDPREV, bool DOLEAKY>
__global__ void __launch_bounds__(256) dec_k(
    const float* __restrict__ prev, const float* __restrict__ attn,
    const float* __restrict__ feat, const float* __restrict__ w,
    const float* __restrict__ bias, float* __restrict__ out)
{
    constexpr int CIN = CP + 1 + CF, Rh = R / 2;
    __shared__ float ws[COG * CIN * 9];
    int t = threadIdx.x, gid = blockIdx.x * 256 + t;
    int tx = gid % Rh;
    int ty = (gid / Rh) % Rh;
    int k = (gid / (Rh * Rh)) & 63;
    int g = gid / (Rh * Rh * 64);

    for (int i = t; i < COG * CIN * 9; i += 256) ws[i] = w[g * COG * CIN * 9 + i];
    __syncthreads();

    float acc[COG][2][2];
#pragma unroll
    for (int cg = 0; cg < COG; ++cg) {
        float b0 = bias[g * COG + cg];
        acc[cg][0][0] = b0; acc[cg][0][1] = b0; acc[cg][1][0] = b0; acc[cg][1][1] = b0;
    }

    bool hr[3], hc[3], fr[4], fc[4];
#pragma unroll
    for (int i = 0; i < 3; ++i) {
        int yy = ty - 1 + i; hr[i] = (yy >= 0) && (yy < Rh);
        int xx = tx - 1 + i; hc[i] = (xx >= 0) && (xx < Rh);
    }
#pragma unroll
    for (int i = 0; i < 4; ++i) {
        int yy = 2 * ty - 1 + i; fr[i] = (yy >= 0) && (yy < R);
        int xx = 2 * tx - 1 + i; fc[i] = (xx >= 0) && (xx < R);
    }

    constexpr int HM0[3] = {0, 1, 1};
    constexpr int HM1[3] = {1, 1, 2};

    int np = TILEDPREV ? (2 + (k & 1)) : k;
    int kf = k & 1;

    for (int ci = 0; ci < CP + 1; ++ci) {
        const float* bp = (ci < CP) ? (prev + ((size_t)(np * CP + ci)) * Rh * Rh)
                                    : (attn + (size_t)k * Rh * Rh);
        bp += (ty - 1) * Rh + (tx - 1);
        float P[3][3];
#pragma unroll
        for (int i = 0; i < 3; ++i)
#pragma unroll
            for (int j = 0; j < 3; ++j)
                P[i][j] = (hr[i] & hc[j]) ? bp[i * Rh + j] : 0.f;
#pragma unroll
        for (int cg = 0; cg < COG; ++cg) {
#pragma unroll
            for (int dy = 0; dy < 3; ++dy) {
#pragma unroll
                for (int dx = 0; dx < 3; ++dx) {
                    float wv = ws[(cg * CIN + ci) * 9 + dy * 3 + dx];
                    acc[cg][0][0] = fmaf(wv, P[HM0[dy]][HM0[dx]], acc[cg][0][0]);
                    acc[cg][0][1] = fmaf(wv, P[HM0[dy]][HM1[dx]], acc[cg][0][1]);
                    acc[cg][1][0] = fmaf(wv, P[HM1[dy]][HM0[dx]], acc[cg][1][0]);
                    acc[cg][1][1] = fmaf(wv, P[HM1[dy]][HM1[dx]], acc[cg][1][1]);
                }
            }
        }
    }

    for (int cf = 0; cf < CF; ++cf) {
        const float* bp = feat + ((size_t)(kf * CF + cf)) * R * R + (2 * ty - 1) * R + (2 * tx - 1);
        float F[4][4];
#pragma unroll
        for (int i = 0; i < 4; ++i)
#pragma unroll
            for (int j = 0; j < 4; ++j)
                F[i][j] = (fr[i] & fc[j]) ? bp[i * R + j] : 0.f;
#pragma unroll
        for (int cg = 0; cg < COG; ++cg) {
#pragma unroll
            for (int dy = 0; dy < 3; ++dy) {
#pragma unroll
                for (int dx = 0; dx < 3; ++dx) {
                    float wv = ws[(cg * CIN + CP + 1 + cf) * 9 + dy * 3 + dx];
                    acc[cg][0][0] = fmaf(wv, F[dy][dx],         acc[cg][0][0]);
                    acc[cg][0][1] = fmaf(wv, F[dy][dx + 1],     acc[cg][0][1]);
                    acc[cg][1][0] = fmaf(wv, F[dy + 1][dx],     acc[cg][1][0]);
                    acc[cg][1][1] = fmaf(wv, F[dy + 1][dx + 1], acc[cg][1][1]);
                }
            }
        }
    }

#pragma unroll
    for (int cg = 0; cg < COG; ++cg) {
        float v00 = acc[cg][0][0], v01 = acc[cg][0][1];
        float v10 = acc[cg][1][0], v11 = acc[cg][1][1];
        if (DOLEAKY) { v00 = leaky(v00); v01 = leaky(v01); v10 = leaky(v10); v11 = leaky(v11); }
        float* op = out + ((size_t)(k * CO + g * COG + cg)) * R * R + (2 * ty) * R + 2 * tx;
        float2 a; a.x = v00; a.y = v01; *(float2*)op = a;
        float2 b2; b2.x = v10; b2.y = v11; *(float2*)(op + R) = b2;
    }
}

// ================= dec2/dec3: 4-k same-parity block, LDS staged, 2x2 quads ===========
// Full-res feat staged with EVEN/ODD column split: plane row = [Fe 9 | Fo 9] so the
// per-thread F reads are lane-stride-1 (no 4-way bank conflicts).
template<int R, int CP, int CF, int CO, int MINW, bool DOLEAKY>
__global__ void __launch_bounds__(256, MINW) deckq_k(
    const float* __restrict__ prev, const float* __restrict__ attn,
    const float* __restrict__ feat, const float* __restrict__ w,
    const float* __restrict__ bias, float* __restrict__ out)
{
    constexpr int CIN = CP + 1 + CF, Rh = R / 2, TX = R / 16;
    __shared__ float sf[CF * 324];          // [cf][18 rows][Fe 9 | Fo 9]
    __shared__ float sh[4][(CP + 1) * 100];
    __shared__ float ws[CO * CIN * 9 + CO];

    int t = threadIdx.x;
    int kg = blockIdx.y;
    int p = kg & 1;
    int kbase = (kg >> 1) * 8 + p;          // k = kbase + 2*j, j=0..3
    int tileY = blockIdx.x / TX, tileX = blockIdx.x % TX;
    int Y0 = 16 * tileY, X0 = 16 * tileX;
    int hy0 = 8 * tileY - 1, hx0 = 8 * tileX - 1;

    for (int i = t; i < CO * CIN * 9; i += 256) ws[i] = w[i];
    if (t < CO) ws[CO * CIN * 9 + t] = bias[t];

    // feat: window rows Y0-1..Y0+16, cols X0-1..X0+16; e/o split on window col
    for (int i = t; i < CF * 324; i += 256) {
        int c = i / 324, rem = i - c * 324;
        int r = rem / 18, wc = rem - r * 18;
        int gy = Y0 - 1 + r, gx = X0 - 1 + wc;
        float v = 0.f;
        if (gy >= 0 && gy < R && gx >= 0 && gx < R)
            v = feat[((size_t)(p * CF + c)) * R * R + gy * R + gx];
        sf[c * 324 + r * 18 + (wc & 1) * 9 + (wc >> 1)] = v;
    }
    for (int i = t; i < CP * 100; i += 256) {
        int c = i / 100, rem = i - c * 100;
        int r = rem / 10, col = rem - r * 10;
        int gy = hy0 + r, gx = hx0 + col;
        bool ok = (gy >= 0) && (gy < Rh) && (gx >= 0) && (gx < Rh);
        int off = gy * Rh + gx;
#pragma unroll
        for (int j = 0; j < 4; ++j) {
            float v = 0.f;
            if (ok) v = prev[((size_t)((kbase + 2 * j) * CP + c)) * Rh * Rh + off];
            sh[j][i] = v;
        }
    }
    if (t < 100) {
        int r = t / 10, col = t - r * 10;
        int gy = hy0 + r, gx = hx0 + col;
        bool ok = (gy >= 0) && (gy < Rh) && (gx >= 0) && (gx < Rh);
        int off = gy * Rh + gx;
#pragma unroll
        for (int j = 0; j < 4; ++j) {
            float v = 0.f;
            if (ok) v = attn[(size_t)(kbase + 2 * j) * Rh * Rh + off];
            sh[j][CP * 100 + t] = v;
        }
    }
    __syncthreads();

    int ksub = t >> 6, q = t & 63, qx = q & 7, qy = q >> 3;
    int k = kbase + 2 * ksub;

    float acc[CO][2][2];
#pragma unroll
    for (int co = 0; co < CO; ++co) {
        float b0 = ws[CO * CIN * 9 + co];
        acc[co][0][0] = b0; acc[co][0][1] = b0; acc[co][1][0] = b0; acc[co][1][1] = b0;
    }

#pragma unroll
    for (int ci = 0; ci < CP + 1; ++ci) {
        const float* hp = &sh[ksub][ci * 100 + qy * 10 + qx];
        float P[3][3];
#pragma unroll
        for (int i = 0; i < 3; ++i)
#pragma unroll
            for (int j = 0; j < 3; ++j) P[i][j] = hp[i * 10 + j];
#pragma unroll
        for (int co = 0; co < CO; ++co) {
#pragma unroll
            for (int dy = 0; dy < 3; ++dy) {
#pragma unroll
                for (int dx = 0; dx < 3; ++dx) {
                    float wv = ws[(co * CIN + ci) * 9 + dy * 3 + dx];
                    acc[co][0][0] = fmaf(wv, P[(0 + dy + 1) >> 1][(0 + dx + 1) >> 1], acc[co][0][0]);
                    acc[co][0][1] = fmaf(wv, P[(0 + dy + 1) >> 1][(1 + dx + 1) >> 1], acc[co][0][1]);
                    acc[co][1][0] = fmaf(wv, P[(1 + dy + 1) >> 1][(0 + dx + 1) >> 1], acc[co][1][0]);
                    acc[co][1][1] = fmaf(wv, P[(1 + dy + 1) >> 1][(1 + dx + 1) >> 1], acc[co][1][1]);
                }
            }
        }
    }
#pragma unroll
    for (int cf = 0; cf < CF; ++cf) {
        const float* fb = &sf[cf * 324];
        float F[4][4];
#pragma unroll
        for (int i = 0; i < 4; ++i) {
            int wr = (2 * qy + i) * 18;
            F[i][0] = fb[wr + qx];
            F[i][1] = fb[wr + 9 + qx];
            F[i][2] = fb[wr + qx + 1];
            F[i][3] = fb[wr + 9 + qx + 1];
        }
#pragma unroll
        for (int co = 0; co < CO; ++co) {
#pragma unroll
            for (int dy = 0; dy < 3; ++dy) {
#pragma unroll
                for (int dx = 0; dx < 3; ++dx) {
                    float wv = ws[(co * CIN + CP + 1 + cf) * 9 + dy * 3 + dx];
                    acc[co][0][0] = fmaf(wv, F[0 + dy][0 + dx], acc[co][0][0]);
                    acc[co][0][1] = fmaf(wv, F[0 + dy][1 + dx], acc[co][0][1]);
                    acc[co][1][0] = fmaf(wv, F[1 + dy][0 + dx], acc[co][1][0]);
                    acc[co][1][1] = fmaf(wv, F[1 + dy][1 + dx], acc[co][1][1]);
                }
            }
        }
    }

#pragma unroll
    for (int co = 0; co < CO; ++co) {
        float v00 = acc[co][0][0], v01 = acc[co][0][1];
        float v10 = acc[co][1][0], v11 = acc[co][1][1];
        if (DOLEAKY) { v00 = leaky(v00); v01 = leaky(v01); v10 = leaky(v10); v11 = leaky(v11); }
        float* op = out + ((size_t)(k * CO + co)) * R * R + (Y0 + 2 * qy) * R + X0 + 2 * qx;
        float2 a; a.x = v00; a.y = v01; *(float2*)op = a;
        float2 b2; b2.x = v10; b2.y = v11; *(float2*)(op + R) = b2;
    }
}

// ================= dec1: 2-k same-parity block, ALL CO=8, staged, 2x1 px/thread ======
// No co-group duplication. Half planes compact 10x10 (runtime row idx handles parity).
// Full-res feat staged with e/o column split (stride-1 LDS reads).
__global__ void __launch_bounds__(256, 2) dec1b_k(
    const float* __restrict__ prev, const float* __restrict__ attn,
    const float* __restrict__ feat, const float* __restrict__ w,
    const float* __restrict__ bias, float* __restrict__ out)
{
    constexpr int R = 64, CP = 16, CF = 16, CIN = 33, Rh = 32, CO = 8;
    __shared__ float sf[CF * 324];          // [cf][18 rows][Fe 9 | Fo 9]
    __shared__ float sh[2][(CP + 1) * 100]; // [ksub][ci][10][10]
    __shared__ float ws[CO * CIN * 9 + CO];

    int t = threadIdx.x;
    int kg = blockIdx.y;                // 0..31
    int p = kg & 1;
    int kbase = (kg >> 1) * 4 + p;      // k = kbase + 2*j, j=0..1
    int tileY = blockIdx.x >> 2, tileX = blockIdx.x & 3;
    int Y0 = 16 * tileY, X0 = 16 * tileX;
    int hy0 = 8 * tileY - 1, hx0 = 8 * tileX - 1;

    for (int i = t; i < CO * CIN * 9; i += 256) ws[i] = w[i];
    if (t < CO) ws[CO * CIN * 9 + t] = bias[t];

    for (int i = t; i < CF * 324; i += 256) {
        int c = i / 324, rem = i - c * 324;
        int r = rem / 18, wc = rem - r * 18;
        int gy = Y0 - 1 + r, gx = X0 - 1 + wc;
        float v = 0.f;
        if (gy >= 0 && gy < R && gx >= 0 && gx < R)
            v = feat[((size_t)(p * CF + c)) * R * R + gy * R + gx];
        sf[c * 324 + r * 18 + (wc & 1) * 9 + (wc >> 1)] = v;
    }
    for (int i = t; i < CP * 100; i += 256) {
        int c = i / 100, rem = i - c * 100;
        int r = rem / 10, col = rem - r * 10;
        int gy = hy0 + r, gx = hx0 + col;
        bool ok = (gy >= 0) && (gy < Rh) && (gx >= 0) && (gx < Rh);
        int off = gy * Rh + gx;
#pragma unroll
        for (int j = 0; j < 2; ++j) {
            float v = 0.f;
            if (ok) v = prev[((size_t)((kbase + 2 * j) * CP + c)) * Rh * Rh + off];
            sh[j][i] = v;
        }
    }
    if (t < 100) {
        int r = t / 10, col = t - r * 10;
        int gy = hy0 + r, gx = hx0 + col;
        bool ok = (gy >= 0) && (gy < Rh) && (gx >= 0) && (gx < Rh);
        int off = gy * Rh + gx;
#pragma unroll
        for (int j = 0; j < 2; ++j) {
            float v = 0.f;
            if (ok) v = attn[(size_t)(kbase + 2 * j) * Rh * Rh + off];
            sh[j][CP * 100 + t] = v;
        }
    }
    __syncthreads();

    int ksub = t >> 7, r2 = t & 127, py = r2 >> 3, px = r2 & 7;
    int k = kbase + 2 * ksub;

    float acc[CO][2];
#pragma unroll
    for (int co = 0; co < CO; ++co) {
        float b0 = ws[CO * CIN * 9 + co];
        acc[co][0] = b0; acc[co][1] = b0;
    }

    // half-window row indices (runtime, parity-safe): rel row for dy = (py+dy+2)>>1
    int rr0 = (py + 1) >> 1;
    int rr1 = (py + 2) >> 1;
    int rr2 = (py + 3) >> 1;

#pragma unroll
    for (int ci = 0; ci < CP + 1; ++ci) {
        const float* hp = &sh[ksub][ci * 100 + px];
        float P[3][3];
#pragma unroll
        for (int j = 0; j < 3; ++j) {
            P[0][j] = hp[rr0 * 10 + j];
            P[1][j] = hp[rr1 * 10 + j];
            P[2][j] = hp[rr2 * 10 + j];
        }
        // col offset per (sx,dx): sx=0 -> {0,1,1}; sx=1 -> {1,1,2}
#pragma unroll
        for (int co = 0; co < CO; ++co) {
#pragma unroll
            for (int dy = 0; dy < 3; ++dy) {
#pragma unroll
                for (int dx = 0; dx < 3; ++dx) {
                    float wv = ws[(co * CIN + ci) * 9 + dy * 3 + dx];
                    acc[co][0] = fmaf(wv, P[dy][(dx + 1) >> 1], acc[co][0]);
                    acc[co][1] = fmaf(wv, P[dy][(dx + 2) >> 1], acc[co][1]);
                }
            }
        }
    }
#pragma unroll
    for (int cf = 0; cf < CF; ++cf) {
        const float* fb = &sf[cf * 324 + py * 18 + px];
        float Fe[3][2], Fo[3][2];
#pragma unroll
        for (int i = 0; i < 3; ++i) {
            Fe[i][0] = fb[i * 18];
            Fe[i][1] = fb[i * 18 + 1];
            Fo[i][0] = fb[i * 18 + 9];
            Fo[i][1] = fb[i * 18 + 10];
        }
        // (sx=0,dx): Fe[dy][0], Fo[dy][0], Fe[dy][1]; (sx=1,dx): Fo[dy][0], Fe[dy][1], Fo[dy][1]
#pragma unroll
        for (int co = 0; co < CO; ++co) {
#pragma unroll
            for (int dy = 0; dy < 3; ++dy) {
                const float* wp = &ws[(co * CIN + CP + 1 + cf) * 9 + dy * 3];
                acc[co][0] = fmaf(wp[0], Fe[dy][0], acc[co][0]);
                acc[co][0] = fmaf(wp[1], Fo[dy][0], acc[co][0]);
                acc[co][0] = fmaf(wp[2], Fe[dy][1], acc[co][0]);
                acc[co][1] = fmaf(wp[0], Fo[dy][0], acc[co][1]);
                acc[co][1] = fmaf(wp[1], Fe[dy][1], acc[co][1]);
                acc[co][1] = fmaf(wp[2], Fo[dy][1], acc[co][1]);
            }
        }
    }

#pragma unroll
    for (int co = 0; co < CO; ++co) {
        float v0 = leaky(acc[co][0]), v1 = leaky(acc[co][1]);
        float* op = out + ((size_t)(k * CO + co)) * R * R + (Y0 + py) * R + X0 + 2 * px;
        float2 a; a.x = v0; a.y = v1; *(float2*)op = a;
    }
}

extern "C" void kernel_launch(void* const* d_in, const int* in_sizes, int n_in,
                              void* d_out, int out_size, void* d_ws, size_t ws_size,
                              hipStream_t stream)
{
    (void)in_sizes; (void)n_in; (void)out_size; (void)ws_size;
    const float* x1 = (const float*)d_in[0];
    const float* x2 = (const float*)d_in[1];
    const int* pts = (const int*)d_in[2];
    const float* ew[4] = {(const float*)d_in[3], (const float*)d_in[5],
                          (const float*)d_in[7], (const float*)d_in[9]};
    const float* eb[4] = {(const float*)d_in[4], (const float*)d_in[6],
                          (const float*)d_in[8], (const float*)d_in[10]};
    const float* dw[4] = {(const float*)d_in[11], (const float*)d_in[13],
                          (const float*)d_in[15], (const float*)d_in[17]};
    const float* db[4] = {(const float*)d_in[12], (const float*)d_in[14],
                          (const float*)d_in[16], (const float*)d_in[18]};

    float* wsp = (float*)d_ws;
    size_t off = 0;
    auto A = [&](size_t n) { float* p = wsp + off; off += n; return p; };

    float* p0 = A((size_t)4 * 4 * 128 * 128);
    float* p1 = A((size_t)4 * 8 * 64 * 64);
    float* p2 = A((size_t)4 * 16 * 32 * 32);
    float* p3 = A((size_t)4 * 16 * 16 * 16);
    float* c2_0 = A((size_t)2 * 4 * 256 * 256);
    float* c2_1 = A((size_t)2 * 8 * 128 * 128);
    float* c2_2 = A((size_t)2 * 16 * 64 * 64);
    float* c2_3 = A((size_t)2 * 16 * 32 * 32);
    float* at0 = A((size_t)64 * 128 * 128);
    float* at1 = A((size_t)64 * 64 * 64);
    float* at2 = A((size_t)64 * 32 * 32);
    float* at3 = A((size_t)64 * 16 * 16);
    float* dec0 = A((size_t)64 * 16 * 32 * 32);
    float* dec1 = A((size_t)64 * 8 * 64 * 64);
    float* dec2 = A((size_t)64 * 4 * 128 * 128);
    float* outp = (float*)d_out;

    // ---- Encoder ----
    { dim3 g(64, 4); enc0_k<<<g, 256, 0, stream>>>(x1, x2, ew[0], eb[0], c2_0, p0); }
    enc_k<128, 4, 8, 2><<<512, 256, 0, stream>>>(p0, p0 + (size_t)2 * 4 * 128 * 128,
                                                 ew[1], eb[1], c2_1, p1);
    enc_k<64, 8, 16, 2><<<256, 256, 0, stream>>>(p1, p1 + (size_t)2 * 8 * 64 * 64,
                                                 ew[2], eb[2], c2_2, p2);
    enc_k<32, 16, 16, 1><<<128, 256, 0, stream>>>(p2, p2 + (size_t)2 * 16 * 32 * 32,
                                                  ew[3], eb[3], c2_3, p3);

    // ---- Attention ----
    { dim3 g(64, 2); attn_k<4, 128, 1><<<g, 256, 0, stream>>>(p0, pts, at0); }
    { dim3 g(16, 2); attn_k<8, 64, 2><<<g, 256, 0, stream>>>(p1, pts, at1); }
    { dim3 g(4, 2);  attn_k<16, 32, 3><<<g, 256, 0, stream>>>(p2, pts, at2); }
    { dim3 g(1, 2);  attn_k<16, 16, 4><<<g, 256, 0, stream>>>(p3, pts, at3); }

    // ---- Decoder ----
    // dec0: unstaged 2x2, COG=4 (4 groups) -> 256 blocks
    dec_k<32, 16, 16, 16, 4, true, true><<<256, 256, 0, stream>>>(p3, at3, c2_3, dw[0], db[0], dec0);
    // dec1: staged, 2-k blocks, full CO=8 -> (16 tiles, 32 k-groups) = 512 blocks
    { dim3 g(16, 32); dec1b_k<<<g, 256, 0, stream>>>(dec0, at2, c2_2, dw[1], db[1], dec1); }
    // dec2: staged 4-k quads: 64 tiles x 16 k-groups
    { dim3 g(64, 16); deckq_k<128, 8, 8, 4, 4, true><<<g, 256, 0, stream>>>(dec1, at1, c2_1, dw[2], db[2], dec2); }
    // dec3: staged 4-k quads: 256 tiles x 16 k-groups
    { dim3 g(256, 16); deckq_k<256, 4, 4, 1, 5, false><<<g, 256, 0, stream>>>(dec2, at0, c2_0, dw[3], db[3], outp); }
}